// Round 8
// baseline (5259.169 us; speedup 1.0000x reference)
//
#include <hip/hip_runtime.h>

#define N_USERS 100000
#define N_ITEMS 50000
#define N_NODES 150000
#define EMBED_DIM 64
#define N_EDGES 4800000
#define N_LAYERS 3

#define BKT_SHIFT 7                                     // 128 rows / bucket
#define BKT_ROWS (1 << BKT_SHIFT)
#define N_BKT ((N_NODES + BKT_ROWS - 1) >> BKT_SHIFT)   // 1172
#define EPB 8192                                        // edges per block (hist/part)
#define NPB ((N_EDGES + EPB - 1) / EPB)                 // 586

// ---------- bf16 helpers (RNE) ----------
__device__ __forceinline__ unsigned short f2bf(float f) {
    unsigned u = __float_as_uint(f);
    u += 0x7fffu + ((u >> 16) & 1u);
    return (unsigned short)(u >> 16);
}
__device__ __forceinline__ float bf2f(unsigned short h) {
    return __uint_as_float((unsigned)h << 16);
}

// ---------------- init: cur0 = bf16(emb) ----------------
__global__ void lgcn_init3(const float* __restrict__ user_emb,
                           const float* __restrict__ item_emb,
                           unsigned short* __restrict__ curb) {
    int i = blockIdx.x * blockDim.x + threadIdx.x;
    const int total = N_NODES * EMBED_DIM / 4;
    if (i >= total) return;
    const int user_elems = N_USERS * EMBED_DIM / 4;
    float4 v;
    if (i < user_elems) v = ((const float4*)user_emb)[i];
    else                v = ((const float4*)item_emb)[i - user_elems];
    ushort4 o;
    o.x = f2bf(v.x); o.y = f2bf(v.y); o.z = f2bf(v.z); o.w = f2bf(v.w);
    ((ushort4*)curb)[i] = o;
}

// ---------------- bucket histogram ----------------
__global__ __launch_bounds__(256)
void k_hist(const int* __restrict__ row, int* __restrict__ bkt_cnt) {
    __shared__ int h[N_BKT];
    for (int i = threadIdx.x; i < N_BKT; i += 256) h[i] = 0;
    __syncthreads();
    int e0 = blockIdx.x * EPB;
    int e1 = e0 + EPB; if (e1 > N_EDGES) e1 = N_EDGES;
    for (int e = e0 + threadIdx.x; e < e1; e += 256)
        atomicAdd(&h[row[e] >> BKT_SHIFT], 1);
    __syncthreads();
    for (int i = threadIdx.x; i < N_BKT; i += 256)
        if (h[i]) atomicAdd(&bkt_cnt[i], h[i]);
}

// ---------------- scan of 1172 bucket counts (chunked parallel) ----------------
#define SCAN_T 256
#define SCAN_C ((N_BKT + SCAN_T - 1) / SCAN_T)   // 5
__global__ void k_scan(const int* __restrict__ bkt_cnt,
                       int* __restrict__ bkt_base,
                       int* __restrict__ bkt_cur) {
    __shared__ int part[SCAN_T];
    int t = threadIdx.x;
    int c0 = t * SCAN_C;
    int local[SCAN_C];
    int run = 0;
    for (int k = 0; k < SCAN_C; ++k) {
        int i = c0 + k;
        int v = (i < N_BKT) ? bkt_cnt[i] : 0;
        local[k] = run;
        run += v;
    }
    part[t] = run;
    __syncthreads();
    if (t == 0) {
        int r2 = 0;
        for (int i = 0; i < SCAN_T; ++i) { int v = part[i]; part[i] = r2; r2 += v; }
    }
    __syncthreads();
    int base = part[t];
    for (int k = 0; k < SCAN_C; ++k) {
        int i = c0 + k;
        if (i < N_BKT) {
            int v = base + local[k];
            bkt_base[i] = v;
            bkt_cur[i]  = v;
        }
    }
    if (t == 0) bkt_base[N_BKT] = N_EDGES;
}

// ---------------- single-pass partition into bucket segments ----------------
// packed edge: (col << 7) | row_local, val bits (int2)
__global__ __launch_bounds__(256)
void k_part(const int* __restrict__ row,
            const int* __restrict__ col,
            const int* __restrict__ valI,
            int* __restrict__ bkt_cur,
            int2* __restrict__ edges) {
    __shared__ int h[N_BKT];
    __shared__ int off[N_BKT];
    int e0 = blockIdx.x * EPB;
    int e1 = e0 + EPB; if (e1 > N_EDGES) e1 = N_EDGES;
    for (int i = threadIdx.x; i < N_BKT; i += 256) h[i] = 0;
    __syncthreads();
    for (int e = e0 + threadIdx.x; e < e1; e += 256)
        atomicAdd(&h[row[e] >> BKT_SHIFT], 1);
    __syncthreads();
    for (int i = threadIdx.x; i < N_BKT; i += 256)
        if (h[i]) off[i] = atomicAdd(&bkt_cur[i], h[i]);
    __syncthreads();
    for (int e = e0 + threadIdx.x; e < e1; e += 256) {
        int r = row[e];
        int b = r >> BKT_SHIFT;
        int p = atomicAdd(&off[b], 1);
        edges[p] = make_int2((col[e] << BKT_SHIFT) | (r & (BKT_ROWS - 1)), valI[e]);
    }
}

// ---------------- per-bucket coarse col-sort (counting, col>>10 bins) ------
// gives each bucket an ascending col sweep at 1024-col granularity so all
// resident blocks traverse x in lockstep (windowed L2 reuse).
__global__ __launch_bounds__(256)
void k_sort_col(const int* __restrict__ bkt_base,
                const int2* __restrict__ edges,
                int2* __restrict__ csr) {
    __shared__ int h[256];
    __shared__ int off[256];
    int b = blockIdx.x;
    int seg0 = bkt_base[b], seg1 = bkt_base[b + 1];
    h[threadIdx.x] = 0;
    __syncthreads();
    for (int e = seg0 + threadIdx.x; e < seg1; e += 256)
        atomicAdd(&h[edges[e].x >> 17], 1);          // col>>10, < 147
    __syncthreads();
    // Hillis-Steele inclusive scan over 256 bins
    for (int o = 1; o < 256; o <<= 1) {
        int t = (threadIdx.x >= o) ? h[threadIdx.x - o] : 0;
        __syncthreads();
        h[threadIdx.x] += t;
        __syncthreads();
    }
    off[threadIdx.x] = threadIdx.x ? h[threadIdx.x - 1] : 0;
    __syncthreads();
    for (int e = seg0 + threadIdx.x; e < seg1; e += 256) {
        int2 ee = edges[e];
        int p = atomicAdd(&off[ee.x >> 17], 1);
        csr[seg0 + p] = ee;
    }
}

// ---------------- windowed SpMM: LDS f32 accumulate, col-lockstep ----------
// one block per 128-row bucket; all 1172 blocks resident (LDS 32KB x 5/CU);
// edges pre-sorted by coarse col -> all blocks sweep x together.
__global__ __launch_bounds__(256, 5)
void lgcn_spmm_win(const int* __restrict__ bkt_base,
                   const int2* __restrict__ cv,
                   const unsigned short* __restrict__ x,   // bf16 [N][64]
                   unsigned short* __restrict__ nxt,       // if !last
                   const unsigned short* __restrict__ e1,  // if last
                   const float* __restrict__ user_emb,
                   const float* __restrict__ item_emb,
                   float* __restrict__ out,                // if last
                   int last) {
    __shared__ float sm[BKT_ROWS * EMBED_DIM];              // 32 KB
    float4* smf4 = (float4*)sm;
    for (int i = threadIdx.x; i < BKT_ROWS * EMBED_DIM / 4; i += 256)
        smf4[i] = make_float4(0.f, 0.f, 0.f, 0.f);
    __syncthreads();

    int b = blockIdx.x;
    int seg0 = bkt_base[b], seg1 = bkt_base[b + 1];
    int wid  = threadIdx.x >> 6;
    int lane = threadIdx.x & 63;
    int cnt  = seg1 - seg0;
    int mend = seg0 + (cnt & ~31);          // 4 waves x 8-edge groups

    for (int base = seg0 + wid * 8; base < mend; base += 32) {
        int2 e0 = cv[base + 0], e1_ = cv[base + 1], e2 = cv[base + 2], e3 = cv[base + 3];
        int2 e4 = cv[base + 4], e5 = cv[base + 5], e6 = cv[base + 6], e7 = cv[base + 7];
        float x0 = bf2f(x[((size_t)(e0.x  >> BKT_SHIFT) << 6) + lane]);
        float x1 = bf2f(x[((size_t)(e1_.x >> BKT_SHIFT) << 6) + lane]);
        float x2 = bf2f(x[((size_t)(e2.x  >> BKT_SHIFT) << 6) + lane]);
        float x3 = bf2f(x[((size_t)(e3.x  >> BKT_SHIFT) << 6) + lane]);
        float x4 = bf2f(x[((size_t)(e4.x  >> BKT_SHIFT) << 6) + lane]);
        float x5 = bf2f(x[((size_t)(e5.x  >> BKT_SHIFT) << 6) + lane]);
        float x6 = bf2f(x[((size_t)(e6.x  >> BKT_SHIFT) << 6) + lane]);
        float x7 = bf2f(x[((size_t)(e7.x  >> BKT_SHIFT) << 6) + lane]);
        atomicAdd(&sm[((e0.x  & (BKT_ROWS - 1)) << 6) + lane], __int_as_float(e0.y)  * x0);
        atomicAdd(&sm[((e1_.x & (BKT_ROWS - 1)) << 6) + lane], __int_as_float(e1_.y) * x1);
        atomicAdd(&sm[((e2.x  & (BKT_ROWS - 1)) << 6) + lane], __int_as_float(e2.y)  * x2);
        atomicAdd(&sm[((e3.x  & (BKT_ROWS - 1)) << 6) + lane], __int_as_float(e3.y)  * x3);
        atomicAdd(&sm[((e4.x  & (BKT_ROWS - 1)) << 6) + lane], __int_as_float(e4.y)  * x4);
        atomicAdd(&sm[((e5.x  & (BKT_ROWS - 1)) << 6) + lane], __int_as_float(e5.y)  * x5);
        atomicAdd(&sm[((e6.x  & (BKT_ROWS - 1)) << 6) + lane], __int_as_float(e6.y)  * x6);
        atomicAdd(&sm[((e7.x  & (BKT_ROWS - 1)) << 6) + lane], __int_as_float(e7.y)  * x7);
    }
    for (int e = mend + wid; e < seg1; e += 4) {
        int2 ee = cv[e];
        float xv = bf2f(x[((size_t)(ee.x >> BKT_SHIFT) << 6) + lane]);
        atomicAdd(&sm[((ee.x & (BKT_ROWS - 1)) << 6) + lane], __int_as_float(ee.y) * xv);
    }
    __syncthreads();

    int row0 = b << BKT_SHIFT;
    int nrows = N_NODES - row0; if (nrows > BKT_ROWS) nrows = BKT_ROWS;
    int total4 = nrows * EMBED_DIM / 4;
    if (!last) {
        ushort4* dst = (ushort4*)(nxt + ((size_t)row0 << 6));
        for (int i = threadIdx.x; i < total4; i += 256) {
            float4 v = smf4[i];
            ushort4 o;
            o.x = f2bf(v.x); o.y = f2bf(v.y); o.z = f2bf(v.z); o.w = f2bf(v.w);
            dst[i] = o;
        }
    } else {
        float* dst = out + ((size_t)row0 << 6);
        const unsigned short* e1p = e1 + ((size_t)row0 << 6);
        const unsigned short* e2p = x  + ((size_t)row0 << 6);
        for (int i = threadIdx.x; i < total4; i += 256) {
            float4 v = smf4[i];
            int gi = (row0 << 6) + i * 4;                 // global element idx (<9.6M)
            float4 z;
            if (gi < N_USERS * EMBED_DIM) z = *(const float4*)(user_emb + gi);
            else                          z = *(const float4*)(item_emb + gi - N_USERS * EMBED_DIM);
            ushort4 w1 = *(const ushort4*)(e1p + i * 4);
            ushort4 w2 = *(const ushort4*)(e2p + i * 4);
            float4 r;
            r.x = ((z.x + bf2f(w1.x)) + bf2f(w2.x) + v.x) * 0.25f;
            r.y = ((z.y + bf2f(w1.y)) + bf2f(w2.y) + v.y) * 0.25f;
            r.z = ((z.z + bf2f(w1.z)) + bf2f(w2.z) + v.z) * 0.25f;
            r.w = ((z.w + bf2f(w1.w)) + bf2f(w2.w) + v.w) * 0.25f;
            *(float4*)(dst + i * 4) = r;
        }
    }
}

// ---------------- fallback (atomic scatter, f32) ----------------
__global__ void lgcn_init(const float* __restrict__ user_emb,
                          const float* __restrict__ item_emb,
                          float* __restrict__ cur,
                          float* __restrict__ acc) {
    int i = blockIdx.x * blockDim.x + threadIdx.x;
    const int total = N_NODES * EMBED_DIM / 4;
    if (i >= total) return;
    const int user_elems = N_USERS * EMBED_DIM / 4;
    float4 v;
    if (i < user_elems) v = ((const float4*)user_emb)[i];
    else                v = ((const float4*)item_emb)[i - user_elems];
    ((float4*)cur)[i] = v;
    ((float4*)acc)[i] = v;
}

__global__ void lgcn_spmm_atomic(const int* __restrict__ row,
                                 const int* __restrict__ col,
                                 const float* __restrict__ val,
                                 const float* __restrict__ x,
                                 float* __restrict__ y) {
    long long t = (long long)blockIdx.x * blockDim.x + threadIdx.x;
    int e = (int)(t >> 6);
    int d = (int)(t & 63);
    if (e >= N_EDGES) return;
    atomicAdd(&y[(long long)row[e] * EMBED_DIM + d],
              val[e] * x[(long long)col[e] * EMBED_DIM + d]);
}

__global__ void lgcn_accum(const float* __restrict__ cur,
                           float* __restrict__ acc, float s) {
    int i = blockIdx.x * blockDim.x + threadIdx.x;
    const int total = N_NODES * EMBED_DIM / 4;
    if (i >= total) return;
    float4 a = ((const float4*)acc)[i];
    float4 c = ((const float4*)cur)[i];
    a.x = (a.x + c.x) * s; a.y = (a.y + c.y) * s;
    a.z = (a.z + c.z) * s; a.w = (a.w + c.w) * s;
    ((float4*)acc)[i] = a;
}

extern "C" void kernel_launch(void* const* d_in, const int* in_sizes, int n_in,
                              void* d_out, int out_size, void* d_ws, size_t ws_size,
                              hipStream_t stream) {
    const int*   adj_row  = (const int*)d_in[0];
    const int*   adj_col  = (const int*)d_in[1];
    const float* adj_val  = (const float*)d_in[2];
    const int*   adj_valI = (const int*)d_in[2];
    const float* user_emb = (const float*)d_in[3];
    const float* item_emb = (const float*)d_in[4];
    float* out = (float*)d_out;

    const size_t buf_elems = (size_t)N_NODES * EMBED_DIM;

    // ---- workspace layout ----
    char* wp = (char*)d_ws;
    int* bkt_cnt  = (int*)wp;  wp += (size_t)N_BKT * sizeof(int);
    int* bkt_base = (int*)wp;  wp += (size_t)(N_BKT + 1) * sizeof(int);
    int* bkt_cur  = (int*)wp;  wp += (size_t)N_BKT * sizeof(int);
    wp = (char*)(((size_t)wp + 63) & ~(size_t)63);
    int2* edges   = (int2*)wp; wp += (size_t)N_EDGES * sizeof(int2);
    wp = (char*)(((size_t)wp + 63) & ~(size_t)63);
    int2* csr_cv  = (int2*)wp; wp += (size_t)N_EDGES * sizeof(int2);
    wp = (char*)(((size_t)wp + 63) & ~(size_t)63);
    unsigned short* curb = (unsigned short*)wp; wp += buf_elems * sizeof(unsigned short);
    unsigned short* nxtb = (unsigned short*)wp; wp += buf_elems * sizeof(unsigned short);
    size_t needed = (size_t)(wp - (char*)d_ws);
    // e2 buffer aliases the (dead-after-sort) edges region
    unsigned short* e2b = (unsigned short*)edges;

    if (needed <= ws_size) {
        // ---- build: bucket partition + per-bucket coarse col-sort ----
        hipMemsetAsync(bkt_cnt, 0, N_BKT * sizeof(int), stream);
        k_hist<<<NPB, 256, 0, stream>>>(adj_row, bkt_cnt);
        k_scan<<<1, SCAN_T, 0, stream>>>(bkt_cnt, bkt_base, bkt_cur);
        k_part<<<NPB, 256, 0, stream>>>(adj_row, adj_col, adj_valI, bkt_cur, edges);
        k_sort_col<<<N_BKT, 256, 0, stream>>>(bkt_base, edges, csr_cv);

        // ---- init cur0 (bf16) ----
        {
            const int total = N_NODES * EMBED_DIM / 4;
            lgcn_init3<<<(total + 255) / 256, 256, 0, stream>>>(user_emb, item_emb, curb);
        }

        // ---- 3 windowed SpMM layers; acc deferred into the last ----
        // L1: curb -> nxtb (e1)
        lgcn_spmm_win<<<N_BKT, 256, 0, stream>>>(bkt_base, csr_cv, curb, nxtb,
                                                 nullptr, nullptr, nullptr, nullptr, 0);
        // L2: nxtb -> e2b (aliases edges)
        lgcn_spmm_win<<<N_BKT, 256, 0, stream>>>(bkt_base, csr_cv, nxtb, e2b,
                                                 nullptr, nullptr, nullptr, nullptr, 0);
        // L3: gather from e2b, combine with e0 (f32 inputs) + e1 + e2 -> out
        lgcn_spmm_win<<<N_BKT, 256, 0, stream>>>(bkt_base, csr_cv, e2b, nullptr,
                                                 nxtb, user_emb, item_emb, out, 1);
    } else {
        // ---- fallback: atomic path (f32) ----
        float* curF = (float*)d_ws;
        float* nxtF = curF + buf_elems;
        const int total = N_NODES * EMBED_DIM / 4;
        lgcn_init<<<(total + 255) / 256, 256, 0, stream>>>(user_emb, item_emb, curF, out);
        float* a = curF; float* b = nxtF;
        for (int layer = 0; layer < N_LAYERS; ++layer) {
            hipMemsetAsync(b, 0, buf_elems * sizeof(float), stream);
            long long tthr = (long long)N_EDGES * 64;
            lgcn_spmm_atomic<<<(unsigned)((tthr + 255) / 256), 256, 0, stream>>>(
                adj_row, adj_col, adj_val, a, b);
            float s = (layer == N_LAYERS - 1) ? (1.0f / (N_LAYERS + 1)) : 1.0f;
            lgcn_accum<<<(total + 255) / 256, 256, 0, stream>>>(b, out, s);
            float* t = a; a = b; b = t;
        }
    }
}

// Round 9
// 5242.001 us; speedup vs baseline: 1.0033x; 1.0033x over previous
//
#include <hip/hip_runtime.h>

#define N_USERS 100000
#define N_ITEMS 50000
#define N_NODES 150000
#define EMBED_DIM 64
#define N_EDGES 4800000
#define N_LAYERS 3

#define BKT_SHIFT 7                                     // 128 rows / bucket
#define BKT_ROWS (1 << BKT_SHIFT)
#define N_BKT ((N_NODES + BKT_ROWS - 1) >> BKT_SHIFT)   // 1172
#define EPB 8192                                        // edges per block (hist/part)
#define NPB ((N_EDGES + EPB - 1) / EPB)                 // 586

// ---------- bf16 helpers (RNE) ----------
__device__ __forceinline__ unsigned short f2bf(float f) {
    unsigned u = __float_as_uint(f);
    u += 0x7fffu + ((u >> 16) & 1u);
    return (unsigned short)(u >> 16);
}
__device__ __forceinline__ float bf2f(unsigned short h) {
    return __uint_as_float((unsigned)h << 16);
}

// ---------- native LDS f32 add (bypasses hipcc's CAS-loop lowering) ----------
// ds_add_f32 is fire-and-forget (no return) -> no dependent round-trip.
// LDS aperture is 4GB-aligned, so low-32 of the generic pointer = LDS offset.
__device__ __forceinline__ void lds_fadd(float* p, float v) {
    unsigned a = (unsigned)(unsigned long long)p;
    asm volatile("ds_add_f32 %0, %1" :: "v"(a), "v"(v) : "memory");
}

// ---------------- init: cur0 = bf16(emb) ----------------
__global__ void lgcn_init3(const float* __restrict__ user_emb,
                           const float* __restrict__ item_emb,
                           unsigned short* __restrict__ curb) {
    int i = blockIdx.x * blockDim.x + threadIdx.x;
    const int total = N_NODES * EMBED_DIM / 4;
    if (i >= total) return;
    const int user_elems = N_USERS * EMBED_DIM / 4;
    float4 v;
    if (i < user_elems) v = ((const float4*)user_emb)[i];
    else                v = ((const float4*)item_emb)[i - user_elems];
    ushort4 o;
    o.x = f2bf(v.x); o.y = f2bf(v.y); o.z = f2bf(v.z); o.w = f2bf(v.w);
    ((ushort4*)curb)[i] = o;
}

// ---------------- bucket histogram ----------------
__global__ __launch_bounds__(256)
void k_hist(const int* __restrict__ row, int* __restrict__ bkt_cnt) {
    __shared__ int h[N_BKT];
    for (int i = threadIdx.x; i < N_BKT; i += 256) h[i] = 0;
    __syncthreads();
    int e0 = blockIdx.x * EPB;
    int e1 = e0 + EPB; if (e1 > N_EDGES) e1 = N_EDGES;
    for (int e = e0 + threadIdx.x; e < e1; e += 256)
        atomicAdd(&h[row[e] >> BKT_SHIFT], 1);
    __syncthreads();
    for (int i = threadIdx.x; i < N_BKT; i += 256)
        if (h[i]) atomicAdd(&bkt_cnt[i], h[i]);
}

// ---------------- scan of 1172 bucket counts (chunked parallel) ----------------
#define SCAN_T 256
#define SCAN_C ((N_BKT + SCAN_T - 1) / SCAN_T)   // 5
__global__ void k_scan(const int* __restrict__ bkt_cnt,
                       int* __restrict__ bkt_base,
                       int* __restrict__ bkt_cur) {
    __shared__ int part[SCAN_T];
    int t = threadIdx.x;
    int c0 = t * SCAN_C;
    int local[SCAN_C];
    int run = 0;
    for (int k = 0; k < SCAN_C; ++k) {
        int i = c0 + k;
        int v = (i < N_BKT) ? bkt_cnt[i] : 0;
        local[k] = run;
        run += v;
    }
    part[t] = run;
    __syncthreads();
    if (t == 0) {
        int r2 = 0;
        for (int i = 0; i < SCAN_T; ++i) { int v = part[i]; part[i] = r2; r2 += v; }
    }
    __syncthreads();
    int base = part[t];
    for (int k = 0; k < SCAN_C; ++k) {
        int i = c0 + k;
        if (i < N_BKT) {
            int v = base + local[k];
            bkt_base[i] = v;
            bkt_cur[i]  = v;
        }
    }
    if (t == 0) bkt_base[N_BKT] = N_EDGES;
}

// ---------------- single-pass partition into bucket segments ----------------
// packed edge: (col << 7) | row_local, val bits (int2)
__global__ __launch_bounds__(256)
void k_part(const int* __restrict__ row,
            const int* __restrict__ col,
            const int* __restrict__ valI,
            int* __restrict__ bkt_cur,
            int2* __restrict__ edges) {
    __shared__ int h[N_BKT];
    __shared__ int off[N_BKT];
    int e0 = blockIdx.x * EPB;
    int e1 = e0 + EPB; if (e1 > N_EDGES) e1 = N_EDGES;
    for (int i = threadIdx.x; i < N_BKT; i += 256) h[i] = 0;
    __syncthreads();
    for (int e = e0 + threadIdx.x; e < e1; e += 256)
        atomicAdd(&h[row[e] >> BKT_SHIFT], 1);
    __syncthreads();
    for (int i = threadIdx.x; i < N_BKT; i += 256)
        if (h[i]) off[i] = atomicAdd(&bkt_cur[i], h[i]);
    __syncthreads();
    for (int e = e0 + threadIdx.x; e < e1; e += 256) {
        int r = row[e];
        int b = r >> BKT_SHIFT;
        int p = atomicAdd(&off[b], 1);
        edges[p] = make_int2((col[e] << BKT_SHIFT) | (r & (BKT_ROWS - 1)), valI[e]);
    }
}

// ---------------- per-bucket coarse col-sort (counting, col>>10 bins) ------
__global__ __launch_bounds__(256)
void k_sort_col(const int* __restrict__ bkt_base,
                const int2* __restrict__ edges,
                int2* __restrict__ csr) {
    __shared__ int h[256];
    __shared__ int off[256];
    int b = blockIdx.x;
    int seg0 = bkt_base[b], seg1 = bkt_base[b + 1];
    h[threadIdx.x] = 0;
    __syncthreads();
    for (int e = seg0 + threadIdx.x; e < seg1; e += 256)
        atomicAdd(&h[edges[e].x >> 17], 1);          // col>>10, < 147
    __syncthreads();
    for (int o = 1; o < 256; o <<= 1) {
        int t = (threadIdx.x >= o) ? h[threadIdx.x - o] : 0;
        __syncthreads();
        h[threadIdx.x] += t;
        __syncthreads();
    }
    off[threadIdx.x] = threadIdx.x ? h[threadIdx.x - 1] : 0;
    __syncthreads();
    for (int e = seg0 + threadIdx.x; e < seg1; e += 256) {
        int2 ee = edges[e];
        int p = atomicAdd(&off[ee.x >> 17], 1);
        csr[seg0 + p] = ee;
    }
}

// ---------------- windowed SpMM: native ds_add_f32, col-lockstep ----------
__global__ __launch_bounds__(256, 5)
void lgcn_spmm_win(const int* __restrict__ bkt_base,
                   const int2* __restrict__ cv,
                   const unsigned short* __restrict__ x,   // bf16 [N][64]
                   unsigned short* __restrict__ nxt,       // if !last
                   const unsigned short* __restrict__ e1,  // if last
                   const float* __restrict__ user_emb,
                   const float* __restrict__ item_emb,
                   float* __restrict__ out,                // if last
                   int last) {
    __shared__ float sm[BKT_ROWS * EMBED_DIM];              // 32 KB
    float4* smf4 = (float4*)sm;
    for (int i = threadIdx.x; i < BKT_ROWS * EMBED_DIM / 4; i += 256)
        smf4[i] = make_float4(0.f, 0.f, 0.f, 0.f);
    __syncthreads();

    int b = blockIdx.x;
    int seg0 = bkt_base[b], seg1 = bkt_base[b + 1];
    int wid  = threadIdx.x >> 6;
    int lane = threadIdx.x & 63;
    int cnt  = seg1 - seg0;
    int mend = seg0 + (cnt & ~31);          // 4 waves x 8-edge groups

    for (int base = seg0 + wid * 8; base < mend; base += 32) {
        int2 e0 = cv[base + 0], e1_ = cv[base + 1], e2 = cv[base + 2], e3 = cv[base + 3];
        int2 e4 = cv[base + 4], e5 = cv[base + 5], e6 = cv[base + 6], e7 = cv[base + 7];
        float x0 = bf2f(x[((size_t)(e0.x  >> BKT_SHIFT) << 6) + lane]);
        float x1 = bf2f(x[((size_t)(e1_.x >> BKT_SHIFT) << 6) + lane]);
        float x2 = bf2f(x[((size_t)(e2.x  >> BKT_SHIFT) << 6) + lane]);
        float x3 = bf2f(x[((size_t)(e3.x  >> BKT_SHIFT) << 6) + lane]);
        float x4 = bf2f(x[((size_t)(e4.x  >> BKT_SHIFT) << 6) + lane]);
        float x5 = bf2f(x[((size_t)(e5.x  >> BKT_SHIFT) << 6) + lane]);
        float x6 = bf2f(x[((size_t)(e6.x  >> BKT_SHIFT) << 6) + lane]);
        float x7 = bf2f(x[((size_t)(e7.x  >> BKT_SHIFT) << 6) + lane]);
        lds_fadd(&sm[((e0.x  & (BKT_ROWS - 1)) << 6) + lane], __int_as_float(e0.y)  * x0);
        lds_fadd(&sm[((e1_.x & (BKT_ROWS - 1)) << 6) + lane], __int_as_float(e1_.y) * x1);
        lds_fadd(&sm[((e2.x  & (BKT_ROWS - 1)) << 6) + lane], __int_as_float(e2.y)  * x2);
        lds_fadd(&sm[((e3.x  & (BKT_ROWS - 1)) << 6) + lane], __int_as_float(e3.y)  * x3);
        lds_fadd(&sm[((e4.x  & (BKT_ROWS - 1)) << 6) + lane], __int_as_float(e4.y)  * x4);
        lds_fadd(&sm[((e5.x  & (BKT_ROWS - 1)) << 6) + lane], __int_as_float(e5.y)  * x5);
        lds_fadd(&sm[((e6.x  & (BKT_ROWS - 1)) << 6) + lane], __int_as_float(e6.y)  * x6);
        lds_fadd(&sm[((e7.x  & (BKT_ROWS - 1)) << 6) + lane], __int_as_float(e7.y)  * x7);
    }
    for (int e = mend + wid; e < seg1; e += 4) {
        int2 ee = cv[e];
        float xv = bf2f(x[((size_t)(ee.x >> BKT_SHIFT) << 6) + lane]);
        lds_fadd(&sm[((ee.x & (BKT_ROWS - 1)) << 6) + lane], __int_as_float(ee.y) * xv);
    }
    // inline-asm DS ops are invisible to the compiler's waitcnt tracking:
    // drain them explicitly before the barrier.
    asm volatile("s_waitcnt lgkmcnt(0)" ::: "memory");
    __syncthreads();

    int row0 = b << BKT_SHIFT;
    int nrows = N_NODES - row0; if (nrows > BKT_ROWS) nrows = BKT_ROWS;
    int total4 = nrows * EMBED_DIM / 4;
    if (!last) {
        ushort4* dst = (ushort4*)(nxt + ((size_t)row0 << 6));
        for (int i = threadIdx.x; i < total4; i += 256) {
            float4 v = smf4[i];
            ushort4 o;
            o.x = f2bf(v.x); o.y = f2bf(v.y); o.z = f2bf(v.z); o.w = f2bf(v.w);
            dst[i] = o;
        }
    } else {
        float* dst = out + ((size_t)row0 << 6);
        const unsigned short* e1p = e1 + ((size_t)row0 << 6);
        const unsigned short* e2p = x  + ((size_t)row0 << 6);
        for (int i = threadIdx.x; i < total4; i += 256) {
            float4 v = smf4[i];
            int gi = (row0 << 6) + i * 4;                 // global element idx (<9.6M)
            float4 z;
            if (gi < N_USERS * EMBED_DIM) z = *(const float4*)(user_emb + gi);
            else                          z = *(const float4*)(item_emb + gi - N_USERS * EMBED_DIM);
            ushort4 w1 = *(const ushort4*)(e1p + i * 4);
            ushort4 w2 = *(const ushort4*)(e2p + i * 4);
            float4 r;
            r.x = ((z.x + bf2f(w1.x)) + bf2f(w2.x) + v.x) * 0.25f;
            r.y = ((z.y + bf2f(w1.y)) + bf2f(w2.y) + v.y) * 0.25f;
            r.z = ((z.z + bf2f(w1.z)) + bf2f(w2.z) + v.z) * 0.25f;
            r.w = ((z.w + bf2f(w1.w)) + bf2f(w2.w) + v.w) * 0.25f;
            *(float4*)(dst + i * 4) = r;
        }
    }
}

// ---------------- fallback (atomic scatter, f32) ----------------
__global__ void lgcn_init(const float* __restrict__ user_emb,
                          const float* __restrict__ item_emb,
                          float* __restrict__ cur,
                          float* __restrict__ acc) {
    int i = blockIdx.x * blockDim.x + threadIdx.x;
    const int total = N_NODES * EMBED_DIM / 4;
    if (i >= total) return;
    const int user_elems = N_USERS * EMBED_DIM / 4;
    float4 v;
    if (i < user_elems) v = ((const float4*)user_emb)[i];
    else                v = ((const float4*)item_emb)[i - user_elems];
    ((float4*)cur)[i] = v;
    ((float4*)acc)[i] = v;
}

__global__ void lgcn_spmm_atomic(const int* __restrict__ row,
                                 const int* __restrict__ col,
                                 const float* __restrict__ val,
                                 const float* __restrict__ x,
                                 float* __restrict__ y) {
    long long t = (long long)blockIdx.x * blockDim.x + threadIdx.x;
    int e = (int)(t >> 6);
    int d = (int)(t & 63);
    if (e >= N_EDGES) return;
    atomicAdd(&y[(long long)row[e] * EMBED_DIM + d],
              val[e] * x[(long long)col[e] * EMBED_DIM + d]);
}

__global__ void lgcn_accum(const float* __restrict__ cur,
                           float* __restrict__ acc, float s) {
    int i = blockIdx.x * blockDim.x + threadIdx.x;
    const int total = N_NODES * EMBED_DIM / 4;
    if (i >= total) return;
    float4 a = ((const float4*)acc)[i];
    float4 c = ((const float4*)cur)[i];
    a.x = (a.x + c.x) * s; a.y = (a.y + c.y) * s;
    a.z = (a.z + c.z) * s; a.w = (a.w + c.w) * s;
    ((float4*)acc)[i] = a;
}

extern "C" void kernel_launch(void* const* d_in, const int* in_sizes, int n_in,
                              void* d_out, int out_size, void* d_ws, size_t ws_size,
                              hipStream_t stream) {
    const int*   adj_row  = (const int*)d_in[0];
    const int*   adj_col  = (const int*)d_in[1];
    const float* adj_val  = (const float*)d_in[2];
    const int*   adj_valI = (const int*)d_in[2];
    const float* user_emb = (const float*)d_in[3];
    const float* item_emb = (const float*)d_in[4];
    float* out = (float*)d_out;

    const size_t buf_elems = (size_t)N_NODES * EMBED_DIM;

    // ---- workspace layout ----
    char* wp = (char*)d_ws;
    int* bkt_cnt  = (int*)wp;  wp += (size_t)N_BKT * sizeof(int);
    int* bkt_base = (int*)wp;  wp += (size_t)(N_BKT + 1) * sizeof(int);
    int* bkt_cur  = (int*)wp;  wp += (size_t)N_BKT * sizeof(int);
    wp = (char*)(((size_t)wp + 63) & ~(size_t)63);
    int2* edges   = (int2*)wp; wp += (size_t)N_EDGES * sizeof(int2);
    wp = (char*)(((size_t)wp + 63) & ~(size_t)63);
    int2* csr_cv  = (int2*)wp; wp += (size_t)N_EDGES * sizeof(int2);
    wp = (char*)(((size_t)wp + 63) & ~(size_t)63);
    unsigned short* curb = (unsigned short*)wp; wp += buf_elems * sizeof(unsigned short);
    unsigned short* nxtb = (unsigned short*)wp; wp += buf_elems * sizeof(unsigned short);
    size_t needed = (size_t)(wp - (char*)d_ws);
    // e2 buffer aliases the (dead-after-sort) edges region
    unsigned short* e2b = (unsigned short*)edges;

    if (needed <= ws_size) {
        // ---- build: bucket partition + per-bucket coarse col-sort ----
        hipMemsetAsync(bkt_cnt, 0, N_BKT * sizeof(int), stream);
        k_hist<<<NPB, 256, 0, stream>>>(adj_row, bkt_cnt);
        k_scan<<<1, SCAN_T, 0, stream>>>(bkt_cnt, bkt_base, bkt_cur);
        k_part<<<NPB, 256, 0, stream>>>(adj_row, adj_col, adj_valI, bkt_cur, edges);
        k_sort_col<<<N_BKT, 256, 0, stream>>>(bkt_base, edges, csr_cv);

        // ---- init cur0 (bf16) ----
        {
            const int total = N_NODES * EMBED_DIM / 4;
            lgcn_init3<<<(total + 255) / 256, 256, 0, stream>>>(user_emb, item_emb, curb);
        }

        // ---- 3 windowed SpMM layers; acc deferred into the last ----
        lgcn_spmm_win<<<N_BKT, 256, 0, stream>>>(bkt_base, csr_cv, curb, nxtb,
                                                 nullptr, nullptr, nullptr, nullptr, 0);
        lgcn_spmm_win<<<N_BKT, 256, 0, stream>>>(bkt_base, csr_cv, nxtb, e2b,
                                                 nullptr, nullptr, nullptr, nullptr, 0);
        lgcn_spmm_win<<<N_BKT, 256, 0, stream>>>(bkt_base, csr_cv, e2b, nullptr,
                                                 nxtb, user_emb, item_emb, out, 1);
    } else {
        // ---- fallback: atomic path (f32) ----
        float* curF = (float*)d_ws;
        float* nxtF = curF + buf_elems;
        const int total = N_NODES * EMBED_DIM / 4;
        lgcn_init<<<(total + 255) / 256, 256, 0, stream>>>(user_emb, item_emb, curF, out);
        float* a = curF; float* b = nxtF;
        for (int layer = 0; layer < N_LAYERS; ++layer) {
            hipMemsetAsync(b, 0, buf_elems * sizeof(float), stream);
            long long tthr = (long long)N_EDGES * 64;
            lgcn_spmm_atomic<<<(unsigned)((tthr + 255) / 256), 256, 0, stream>>>(
                adj_row, adj_col, adj_val, a, b);
            float s = (layer == N_LAYERS - 1) ? (1.0f / (N_LAYERS + 1)) : 1.0f;
            lgcn_accum<<<(total + 255) / 256, 256, 0, stream>>>(b, out, s);
            float* t = a; a = b; b = t;
        }
    }
}

// Round 10
// 678.513 us; speedup vs baseline: 7.7510x; 7.7257x over previous
//
#include <hip/hip_runtime.h>

#define N_USERS 100000
#define N_ITEMS 50000
#define N_NODES 150000
#define EMBED_DIM 64
#define N_EDGES 4800000
#define N_LAYERS 3

#define BKT_SHIFT 7                                     // 128 rows / bucket
#define BKT_ROWS (1 << BKT_SHIFT)
#define N_BKT ((N_NODES + BKT_ROWS - 1) >> BKT_SHIFT)   // 1172
#define EPB 8192                                        // edges per block (hist/part)
#define NPB ((N_EDGES + EPB - 1) / EPB)                 // 586
#define INIT_BLOCKS ((N_NODES * EMBED_DIM / 4 + 255) / 256)   // 9375

typedef float f32x4 __attribute__((ext_vector_type(4)));

// ---------- bf16 helpers (RNE) ----------
__device__ __forceinline__ unsigned short f2bf(float f) {
    unsigned u = __float_as_uint(f);
    u += 0x7fffu + ((u >> 16) & 1u);
    return (unsigned short)(u >> 16);
}
__device__ __forceinline__ float bf2f(unsigned short h) {
    return __uint_as_float((unsigned)h << 16);
}

// ---------- non-temporal helpers (one-touch streams: don't pollute L2) ----------
__device__ __forceinline__ int2 nt_ld_int2(const int2* p) {
    unsigned long long raw = __builtin_nontemporal_load((const unsigned long long*)p);
    int2 r; r.x = (int)(unsigned)(raw & 0xffffffffull); r.y = (int)(raw >> 32);
    return r;
}
__device__ __forceinline__ int nt_ld_i32(const int* p) {
    return __builtin_nontemporal_load(p);
}

// ---------------- fused: bucket histogram + init cur0=bf16(emb) ----------------
__global__ __launch_bounds__(256)
void k_hist_init(const int* __restrict__ row, int* __restrict__ bkt_cnt,
                 const float* __restrict__ user_emb,
                 const float* __restrict__ item_emb,
                 unsigned short* __restrict__ curb) {
    __shared__ int h[N_BKT];
    int blk = blockIdx.x;
    if (blk < NPB) {
        for (int i = threadIdx.x; i < N_BKT; i += 256) h[i] = 0;
        __syncthreads();
        int e0 = blk * EPB;
        int e1 = e0 + EPB; if (e1 > N_EDGES) e1 = N_EDGES;
        for (int e = e0 + threadIdx.x; e < e1; e += 256)
            atomicAdd(&h[nt_ld_i32(&row[e]) >> BKT_SHIFT], 1);
        __syncthreads();
        for (int i = threadIdx.x; i < N_BKT; i += 256)
            if (h[i]) atomicAdd(&bkt_cnt[i], h[i]);
    } else {
        int i = (blk - NPB) * 256 + threadIdx.x;
        const int total = N_NODES * EMBED_DIM / 4;
        if (i >= total) return;
        const int user_elems = N_USERS * EMBED_DIM / 4;
        f32x4 v;
        if (i < user_elems) v = __builtin_nontemporal_load((const f32x4*)user_emb + i);
        else                v = __builtin_nontemporal_load((const f32x4*)item_emb + (i - user_elems));
        unsigned long long w =  (unsigned long long)f2bf(v.x)
                             | ((unsigned long long)f2bf(v.y) << 16)
                             | ((unsigned long long)f2bf(v.z) << 32)
                             | ((unsigned long long)f2bf(v.w) << 48);
        __builtin_nontemporal_store(w, (unsigned long long*)curb + i);
    }
}

// ---------------- scan of 1172 bucket counts (chunked parallel) ----------------
#define SCAN_T 256
#define SCAN_C ((N_BKT + SCAN_T - 1) / SCAN_T)   // 5
__global__ void k_scan(const int* __restrict__ bkt_cnt,
                       int* __restrict__ bkt_base,
                       int* __restrict__ bkt_cur) {
    __shared__ int part[SCAN_T];
    int t = threadIdx.x;
    int c0 = t * SCAN_C;
    int local[SCAN_C];
    int run = 0;
    for (int k = 0; k < SCAN_C; ++k) {
        int i = c0 + k;
        int v = (i < N_BKT) ? bkt_cnt[i] : 0;
        local[k] = run;
        run += v;
    }
    part[t] = run;
    __syncthreads();
    if (t == 0) {
        int r2 = 0;
        for (int i = 0; i < SCAN_T; ++i) { int v = part[i]; part[i] = r2; r2 += v; }
    }
    __syncthreads();
    int base = part[t];
    for (int k = 0; k < SCAN_C; ++k) {
        int i = c0 + k;
        if (i < N_BKT) {
            int v = base + local[k];
            bkt_base[i] = v;
            bkt_cur[i]  = v;
        }
    }
    if (t == 0) bkt_base[N_BKT] = N_EDGES;
}

// ---------------- single-pass partition into bucket segments ----------------
// packed edge: (col << 7) | row_local, val bits (int2)
__global__ __launch_bounds__(256)
void k_part(const int* __restrict__ row,
            const int* __restrict__ col,
            const int* __restrict__ valI,
            int* __restrict__ bkt_cur,
            int2* __restrict__ edges) {
    __shared__ int h[N_BKT];
    __shared__ int off[N_BKT];
    int e0 = blockIdx.x * EPB;
    int e1 = e0 + EPB; if (e1 > N_EDGES) e1 = N_EDGES;
    for (int i = threadIdx.x; i < N_BKT; i += 256) h[i] = 0;
    __syncthreads();
    for (int e = e0 + threadIdx.x; e < e1; e += 256)
        atomicAdd(&h[nt_ld_i32(&row[e]) >> BKT_SHIFT], 1);
    __syncthreads();
    for (int i = threadIdx.x; i < N_BKT; i += 256)
        if (h[i]) off[i] = atomicAdd(&bkt_cur[i], h[i]);
    __syncthreads();
    for (int e = e0 + threadIdx.x; e < e1; e += 256) {
        int r = nt_ld_i32(&row[e]);
        int b = r >> BKT_SHIFT;
        int p = atomicAdd(&off[b], 1);
        edges[p] = make_int2((nt_ld_i32(&col[e]) << BKT_SHIFT) | (r & (BKT_ROWS - 1)),
                             nt_ld_i32(&valI[e]));
    }
}

// ---------------- per-bucket counting sort -> row-sorted CSR + rowptr ------
__global__ __launch_bounds__(256)
void k_sort(const int* __restrict__ bkt_base,
            const int2* __restrict__ edges,
            int2* __restrict__ csr,
            int* __restrict__ rowptr) {
    __shared__ int h[BKT_ROWS];
    __shared__ int off[BKT_ROWS];
    int b = blockIdx.x;
    int seg0 = bkt_base[b], seg1 = bkt_base[b + 1];
    if (threadIdx.x < BKT_ROWS) h[threadIdx.x] = 0;
    __syncthreads();
    for (int e = seg0 + threadIdx.x; e < seg1; e += 256)
        atomicAdd(&h[edges[e].x & (BKT_ROWS - 1)], 1);
    __syncthreads();
    // parallel Hillis-Steele inclusive scan over h[0..127]
    for (int o = 1; o < BKT_ROWS; o <<= 1) {
        int t = 0;
        if (threadIdx.x < BKT_ROWS && threadIdx.x >= o) t = h[threadIdx.x - o];
        __syncthreads();
        if (threadIdx.x < BKT_ROWS) h[threadIdx.x] += t;
        __syncthreads();
    }
    int row0 = b << BKT_SHIFT;
    int nrows = N_NODES - row0; if (nrows > BKT_ROWS) nrows = BKT_ROWS;
    if (threadIdx.x < BKT_ROWS) {
        int excl = threadIdx.x ? h[threadIdx.x - 1] : 0;
        off[threadIdx.x] = excl;
        if (threadIdx.x < nrows) rowptr[row0 + threadIdx.x] = seg0 + excl;
    }
    __syncthreads();
    for (int e = seg0 + threadIdx.x; e < seg1; e += 256) {
        int2 ee = edges[e];
        int rl = ee.x & (BKT_ROWS - 1);
        int p = atomicAdd(&off[rl], 1);
        csr[seg0 + p] = make_int2(ee.x >> BKT_SHIFT, ee.y);   // (col, val bits)
    }
    if (b == N_BKT - 1 && threadIdx.x == 0) rowptr[N_NODES] = N_EDGES;
}

// ---------------- gather core: 8-deep MLP dot over one row ----------------
// cv loads are non-temporal (one-touch stream); x gathers stay cached (reuse).
__device__ __forceinline__ float spmv_row(const int2* __restrict__ cv,
                                          const unsigned short* __restrict__ x,
                                          int start, int end, int lane) {
    float a0 = 0.f, a1 = 0.f, a2 = 0.f, a3 = 0.f;
    float a4 = 0.f, a5 = 0.f, a6 = 0.f, a7 = 0.f;
    int j = start;
    for (; j + 8 <= end; j += 8) {
        int2 e0 = nt_ld_int2(&cv[j + 0]), e1 = nt_ld_int2(&cv[j + 1]);
        int2 e2 = nt_ld_int2(&cv[j + 2]), e3 = nt_ld_int2(&cv[j + 3]);
        int2 e4 = nt_ld_int2(&cv[j + 4]), e5 = nt_ld_int2(&cv[j + 5]);
        int2 e6 = nt_ld_int2(&cv[j + 6]), e7 = nt_ld_int2(&cv[j + 7]);
        float x0 = bf2f(x[((size_t)e0.x << 6) + lane]);
        float x1 = bf2f(x[((size_t)e1.x << 6) + lane]);
        float x2 = bf2f(x[((size_t)e2.x << 6) + lane]);
        float x3 = bf2f(x[((size_t)e3.x << 6) + lane]);
        float x4 = bf2f(x[((size_t)e4.x << 6) + lane]);
        float x5 = bf2f(x[((size_t)e5.x << 6) + lane]);
        float x6 = bf2f(x[((size_t)e6.x << 6) + lane]);
        float x7 = bf2f(x[((size_t)e7.x << 6) + lane]);
        a0 += __int_as_float(e0.y) * x0;
        a1 += __int_as_float(e1.y) * x1;
        a2 += __int_as_float(e2.y) * x2;
        a3 += __int_as_float(e3.y) * x3;
        a4 += __int_as_float(e4.y) * x4;
        a5 += __int_as_float(e5.y) * x5;
        a6 += __int_as_float(e6.y) * x6;
        a7 += __int_as_float(e7.y) * x7;
    }
    if (j + 4 <= end) {
        int2 e0 = nt_ld_int2(&cv[j + 0]), e1 = nt_ld_int2(&cv[j + 1]);
        int2 e2 = nt_ld_int2(&cv[j + 2]), e3 = nt_ld_int2(&cv[j + 3]);
        a0 += __int_as_float(e0.y) * bf2f(x[((size_t)e0.x << 6) + lane]);
        a1 += __int_as_float(e1.y) * bf2f(x[((size_t)e1.x << 6) + lane]);
        a2 += __int_as_float(e2.y) * bf2f(x[((size_t)e2.x << 6) + lane]);
        a3 += __int_as_float(e3.y) * bf2f(x[((size_t)e3.x << 6) + lane]);
        j += 4;
    }
    for (; j < end; ++j) {
        int2 e = nt_ld_int2(&cv[j]);
        a0 += __int_as_float(e.y) * bf2f(x[((size_t)e.x << 6) + lane]);
    }
    return ((a0 + a1) + (a2 + a3)) + ((a4 + a5) + (a6 + a7));
}

// ---------------- layers 1..L-1: gather SpMV, write bf16 nxt only ----------------
__global__ __launch_bounds__(256)
void lgcn_spmv_mid(const int* __restrict__ rowptr,
                   const int2* __restrict__ cv,
                   const unsigned short* __restrict__ x,
                   unsigned short* __restrict__ nxt) {
    int t = blockIdx.x * blockDim.x + threadIdx.x;
    int wave = t >> 6;
    int lane = t & 63;
    if (wave >= N_NODES) return;
    int r = __builtin_amdgcn_readfirstlane(wave);
    float sum = spmv_row(cv, x, rowptr[r], rowptr[r + 1], lane);
    __builtin_nontemporal_store(f2bf(sum), &nxt[((size_t)r << 6) + lane]);
}

// ---------------- last layer: gather + fused final combine ----------------
// out = (e0_f32 + e1 + e2 + s3) * 0.25 ; x IS e2.
__global__ __launch_bounds__(256)
void lgcn_spmv_last(const int* __restrict__ rowptr,
                    const int2* __restrict__ cv,
                    const unsigned short* __restrict__ x,     // e2 (bf16)
                    const unsigned short* __restrict__ e1,    // layer-1 out (bf16)
                    const float* __restrict__ user_emb,
                    const float* __restrict__ item_emb,
                    float* __restrict__ out) {
    int t = blockIdx.x * blockDim.x + threadIdx.x;
    int wave = t >> 6;
    int lane = t & 63;
    if (wave >= N_NODES) return;
    int r = __builtin_amdgcn_readfirstlane(wave);
    float sum = spmv_row(cv, x, rowptr[r], rowptr[r + 1], lane);
    size_t o = ((size_t)r << 6) + lane;
    float e0 = (r < N_USERS)
        ? __builtin_nontemporal_load(&user_emb[o])
        : __builtin_nontemporal_load(&item_emb[o - ((size_t)N_USERS << 6)]);
    unsigned short w1 = __builtin_nontemporal_load(&e1[o]);
    float v = ((e0 + bf2f(w1)) + bf2f(x[o])) + sum;
    __builtin_nontemporal_store(v * 0.25f, &out[o]);
}

// ---------------- fallback (atomic scatter, f32) ----------------
__global__ void lgcn_init(const float* __restrict__ user_emb,
                          const float* __restrict__ item_emb,
                          float* __restrict__ cur,
                          float* __restrict__ acc) {
    int i = blockIdx.x * blockDim.x + threadIdx.x;
    const int total = N_NODES * EMBED_DIM / 4;
    if (i >= total) return;
    const int user_elems = N_USERS * EMBED_DIM / 4;
    float4 v;
    if (i < user_elems) v = ((const float4*)user_emb)[i];
    else                v = ((const float4*)item_emb)[i - user_elems];
    ((float4*)cur)[i] = v;
    ((float4*)acc)[i] = v;
}

__global__ void lgcn_spmm_atomic(const int* __restrict__ row,
                                 const int* __restrict__ col,
                                 const float* __restrict__ val,
                                 const float* __restrict__ x,
                                 float* __restrict__ y) {
    long long t = (long long)blockIdx.x * blockDim.x + threadIdx.x;
    int e = (int)(t >> 6);
    int d = (int)(t & 63);
    if (e >= N_EDGES) return;
    atomicAdd(&y[(long long)row[e] * EMBED_DIM + d],
              val[e] * x[(long long)col[e] * EMBED_DIM + d]);
}

__global__ void lgcn_accum(const float* __restrict__ cur,
                           float* __restrict__ acc, float s) {
    int i = blockIdx.x * blockDim.x + threadIdx.x;
    const int total = N_NODES * EMBED_DIM / 4;
    if (i >= total) return;
    float4 a = ((const float4*)acc)[i];
    float4 c = ((const float4*)cur)[i];
    a.x = (a.x + c.x) * s; a.y = (a.y + c.y) * s;
    a.z = (a.z + c.z) * s; a.w = (a.w + c.w) * s;
    ((float4*)acc)[i] = a;
}

extern "C" void kernel_launch(void* const* d_in, const int* in_sizes, int n_in,
                              void* d_out, int out_size, void* d_ws, size_t ws_size,
                              hipStream_t stream) {
    const int*   adj_row  = (const int*)d_in[0];
    const int*   adj_col  = (const int*)d_in[1];
    const float* adj_val  = (const float*)d_in[2];
    const int*   adj_valI = (const int*)d_in[2];
    const float* user_emb = (const float*)d_in[3];
    const float* item_emb = (const float*)d_in[4];
    float* out = (float*)d_out;

    const size_t buf_elems = (size_t)N_NODES * EMBED_DIM;

    // ---- workspace layout ----
    char* wp = (char*)d_ws;
    int* bkt_cnt  = (int*)wp;  wp += (size_t)N_BKT * sizeof(int);
    int* bkt_base = (int*)wp;  wp += (size_t)(N_BKT + 1) * sizeof(int);
    int* bkt_cur  = (int*)wp;  wp += (size_t)N_BKT * sizeof(int);
    int* rowptr   = (int*)wp;  wp += (size_t)(N_NODES + 1) * sizeof(int);
    wp = (char*)(((size_t)wp + 63) & ~(size_t)63);
    int2* edges   = (int2*)wp; wp += (size_t)N_EDGES * sizeof(int2);
    wp = (char*)(((size_t)wp + 63) & ~(size_t)63);
    int2* csr_cv  = (int2*)wp; wp += (size_t)N_EDGES * sizeof(int2);
    wp = (char*)(((size_t)wp + 63) & ~(size_t)63);
    unsigned short* curb = (unsigned short*)wp; wp += buf_elems * sizeof(unsigned short);
    unsigned short* nxtb = (unsigned short*)wp; wp += buf_elems * sizeof(unsigned short);
    size_t needed = (size_t)(wp - (char*)d_ws);
    // e2 buffer aliases the (dead-after-sort) edges region
    unsigned short* e2b = (unsigned short*)edges;

    if (needed <= ws_size) {
        // ---- build: fused hist+init, scan, bucket partition, row sort ----
        hipMemsetAsync(bkt_cnt, 0, N_BKT * sizeof(int), stream);
        k_hist_init<<<NPB + INIT_BLOCKS, 256, 0, stream>>>(adj_row, bkt_cnt,
                                                           user_emb, item_emb, curb);
        k_scan<<<1, SCAN_T, 0, stream>>>(bkt_cnt, bkt_base, bkt_cur);
        k_part<<<NPB, 256, 0, stream>>>(adj_row, adj_col, adj_valI, bkt_cur, edges);
        k_sort<<<N_BKT, 256, 0, stream>>>(bkt_base, edges, csr_cv, rowptr);

        // ---- 3 gather-SpMV layers; acc deferred into the last ----
        const long long tthreads = (long long)N_NODES * 64;
        const int nblk = (int)((tthreads + 255) / 256);
        // L1: curb -> nxtb (e1)
        lgcn_spmv_mid<<<nblk, 256, 0, stream>>>(rowptr, csr_cv, curb, nxtb);
        // L2: nxtb -> e2b (aliases edges)
        lgcn_spmv_mid<<<nblk, 256, 0, stream>>>(rowptr, csr_cv, nxtb, e2b);
        // L3: gather from e2b, combine with e0 (f32 inputs) + e1 + e2 -> out
        lgcn_spmv_last<<<nblk, 256, 0, stream>>>(rowptr, csr_cv, e2b, nxtb,
                                                 user_emb, item_emb, out);
    } else {
        // ---- fallback: atomic path (f32) ----
        float* curF = (float*)d_ws;
        float* nxtF = curF + buf_elems;
        const int total = N_NODES * EMBED_DIM / 4;
        lgcn_init<<<(total + 255) / 256, 256, 0, stream>>>(user_emb, item_emb, curF, out);
        float* a = curF; float* b = nxtF;
        for (int layer = 0; layer < N_LAYERS; ++layer) {
            hipMemsetAsync(b, 0, buf_elems * sizeof(float), stream);
            long long tthr = (long long)N_EDGES * 64;
            lgcn_spmm_atomic<<<(unsigned)((tthr + 255) / 256), 256, 0, stream>>>(
                adj_row, adj_col, adj_val, a, b);
            float s = (layer == N_LAYERS - 1) ? (1.0f / (N_LAYERS + 1)) : 1.0f;
            lgcn_accum<<<(total + 255) / 256, 256, 0, stream>>>(b, out, s);
            float* t = a; a = b; b = t;
        }
    }
}

// Round 11
// 643.375 us; speedup vs baseline: 8.1743x; 1.0546x over previous
//
#include <hip/hip_runtime.h>

#define N_USERS 100000
#define N_ITEMS 50000
#define N_NODES 150000
#define EMBED_DIM 64
#define N_EDGES 4800000
#define N_LAYERS 3

#define BKT_SHIFT 7                                     // 128 rows / bucket
#define BKT_ROWS (1 << BKT_SHIFT)
#define N_BKT ((N_NODES + BKT_ROWS - 1) >> BKT_SHIFT)   // 1172
#define EPB 16384                                       // edges per block (hist/part)
#define NPB ((N_EDGES + EPB - 1) / EPB)                 // 293
#define INIT_BLOCKS ((N_NODES * EMBED_DIM / 4 + 255) / 256)   // 9375

// ---------- bf16 helpers (RNE) ----------
__device__ __forceinline__ unsigned short f2bf(float f) {
    unsigned u = __float_as_uint(f);
    u += 0x7fffu + ((u >> 16) & 1u);
    return (unsigned short)(u >> 16);
}
__device__ __forceinline__ float bf2f(unsigned short h) {
    return __uint_as_float((unsigned)h << 16);
}

// ---------------- fused: bucket histogram + init cur0=bf16(emb) ----------------
__global__ __launch_bounds__(256)
void k_hist_init(const int* __restrict__ row, int* __restrict__ bkt_cnt,
                 const float* __restrict__ user_emb,
                 const float* __restrict__ item_emb,
                 unsigned short* __restrict__ curb) {
    __shared__ int h[N_BKT];
    int blk = blockIdx.x;
    if (blk < NPB) {
        for (int i = threadIdx.x; i < N_BKT; i += 256) h[i] = 0;
        __syncthreads();
        int e0 = blk * EPB;
        int e1 = e0 + EPB; if (e1 > N_EDGES) e1 = N_EDGES;
        for (int e = e0 + threadIdx.x; e < e1; e += 256)
            atomicAdd(&h[row[e] >> BKT_SHIFT], 1);
        __syncthreads();
        for (int i = threadIdx.x; i < N_BKT; i += 256)
            if (h[i]) atomicAdd(&bkt_cnt[i], h[i]);
    } else {
        int i = (blk - NPB) * 256 + threadIdx.x;
        const int total = N_NODES * EMBED_DIM / 4;
        if (i >= total) return;
        const int user_elems = N_USERS * EMBED_DIM / 4;
        float4 v;
        if (i < user_elems) v = ((const float4*)user_emb)[i];
        else                v = ((const float4*)item_emb)[i - user_elems];
        ushort4 o;
        o.x = f2bf(v.x); o.y = f2bf(v.y); o.z = f2bf(v.z); o.w = f2bf(v.w);
        ((ushort4*)curb)[i] = o;
    }
}

// ---------------- scan of 1172 bucket counts (chunked parallel) ----------------
#define SCAN_T 256
#define SCAN_C ((N_BKT + SCAN_T - 1) / SCAN_T)   // 5
__global__ void k_scan(const int* __restrict__ bkt_cnt,
                       int* __restrict__ bkt_base,
                       int* __restrict__ bkt_cur) {
    __shared__ int part[SCAN_T];
    int t = threadIdx.x;
    int c0 = t * SCAN_C;
    int local[SCAN_C];
    int run = 0;
    for (int k = 0; k < SCAN_C; ++k) {
        int i = c0 + k;
        int v = (i < N_BKT) ? bkt_cnt[i] : 0;
        local[k] = run;
        run += v;
    }
    part[t] = run;
    __syncthreads();
    if (t == 0) {
        int r2 = 0;
        for (int i = 0; i < SCAN_T; ++i) { int v = part[i]; part[i] = r2; r2 += v; }
    }
    __syncthreads();
    int base = part[t];
    for (int k = 0; k < SCAN_C; ++k) {
        int i = c0 + k;
        if (i < N_BKT) {
            int v = base + local[k];
            bkt_base[i] = v;
            bkt_cur[i]  = v;
        }
    }
    if (t == 0) bkt_base[N_BKT] = N_EDGES;
}

// ---------------- single-pass partition into bucket segments ----------------
// packed edge: (col << 7) | row_local, val bits (int2)
__global__ __launch_bounds__(256)
void k_part(const int* __restrict__ row,
            const int* __restrict__ col,
            const int* __restrict__ valI,
            int* __restrict__ bkt_cur,
            int2* __restrict__ edges) {
    __shared__ int h[N_BKT];
    __shared__ int off[N_BKT];
    int e0 = blockIdx.x * EPB;
    int e1 = e0 + EPB; if (e1 > N_EDGES) e1 = N_EDGES;
    for (int i = threadIdx.x; i < N_BKT; i += 256) h[i] = 0;
    __syncthreads();
    for (int e = e0 + threadIdx.x; e < e1; e += 256)
        atomicAdd(&h[row[e] >> BKT_SHIFT], 1);
    __syncthreads();
    for (int i = threadIdx.x; i < N_BKT; i += 256)
        if (h[i]) off[i] = atomicAdd(&bkt_cur[i], h[i]);
    __syncthreads();
    for (int e = e0 + threadIdx.x; e < e1; e += 256) {
        int r = row[e];
        int b = r >> BKT_SHIFT;
        int p = atomicAdd(&off[b], 1);
        edges[p] = make_int2((col[e] << BKT_SHIFT) | (r & (BKT_ROWS - 1)), valI[e]);
    }
}

// ---------------- per-bucket counting sort -> row-sorted CSR + rowptr ------
__global__ __launch_bounds__(256)
void k_sort(const int* __restrict__ bkt_base,
            const int2* __restrict__ edges,
            int2* __restrict__ csr,
            int* __restrict__ rowptr) {
    __shared__ int h[BKT_ROWS];
    __shared__ int off[BKT_ROWS];
    int b = blockIdx.x;
    int seg0 = bkt_base[b], seg1 = bkt_base[b + 1];
    if (threadIdx.x < BKT_ROWS) h[threadIdx.x] = 0;
    __syncthreads();
    for (int e = seg0 + threadIdx.x; e < seg1; e += 256)
        atomicAdd(&h[edges[e].x & (BKT_ROWS - 1)], 1);
    __syncthreads();
    // parallel Hillis-Steele inclusive scan over h[0..127]
    for (int o = 1; o < BKT_ROWS; o <<= 1) {
        int t = 0;
        if (threadIdx.x < BKT_ROWS && threadIdx.x >= o) t = h[threadIdx.x - o];
        __syncthreads();
        if (threadIdx.x < BKT_ROWS) h[threadIdx.x] += t;
        __syncthreads();
    }
    int row0 = b << BKT_SHIFT;
    int nrows = N_NODES - row0; if (nrows > BKT_ROWS) nrows = BKT_ROWS;
    if (threadIdx.x < BKT_ROWS) {
        int excl = threadIdx.x ? h[threadIdx.x - 1] : 0;
        off[threadIdx.x] = excl;
        if (threadIdx.x < nrows) rowptr[row0 + threadIdx.x] = seg0 + excl;
    }
    __syncthreads();
    for (int e = seg0 + threadIdx.x; e < seg1; e += 256) {
        int2 ee = edges[e];
        int rl = ee.x & (BKT_ROWS - 1);
        int p = atomicAdd(&off[rl], 1);
        csr[seg0 + p] = make_int2(ee.x >> BKT_SHIFT, ee.y);   // (col, val bits)
    }
    if (b == N_BKT - 1 && threadIdx.x == 0) rowptr[N_NODES] = N_EDGES;
}

// ---------------- gather core: 8-deep MLP dot over one row ----------------
__device__ __forceinline__ float spmv_row(const int2* __restrict__ cv,
                                          const unsigned short* __restrict__ x,
                                          int start, int end, int lane) {
    float a0 = 0.f, a1 = 0.f, a2 = 0.f, a3 = 0.f;
    float a4 = 0.f, a5 = 0.f, a6 = 0.f, a7 = 0.f;
    int j = start;
    for (; j + 8 <= end; j += 8) {
        int2 e0 = cv[j + 0], e1 = cv[j + 1], e2 = cv[j + 2], e3 = cv[j + 3];
        int2 e4 = cv[j + 4], e5 = cv[j + 5], e6 = cv[j + 6], e7 = cv[j + 7];
        float x0 = bf2f(x[((size_t)e0.x << 6) + lane]);
        float x1 = bf2f(x[((size_t)e1.x << 6) + lane]);
        float x2 = bf2f(x[((size_t)e2.x << 6) + lane]);
        float x3 = bf2f(x[((size_t)e3.x << 6) + lane]);
        float x4 = bf2f(x[((size_t)e4.x << 6) + lane]);
        float x5 = bf2f(x[((size_t)e5.x << 6) + lane]);
        float x6 = bf2f(x[((size_t)e6.x << 6) + lane]);
        float x7 = bf2f(x[((size_t)e7.x << 6) + lane]);
        a0 += __int_as_float(e0.y) * x0;
        a1 += __int_as_float(e1.y) * x1;
        a2 += __int_as_float(e2.y) * x2;
        a3 += __int_as_float(e3.y) * x3;
        a4 += __int_as_float(e4.y) * x4;
        a5 += __int_as_float(e5.y) * x5;
        a6 += __int_as_float(e6.y) * x6;
        a7 += __int_as_float(e7.y) * x7;
    }
    if (j + 4 <= end) {
        int2 e0 = cv[j + 0], e1 = cv[j + 1], e2 = cv[j + 2], e3 = cv[j + 3];
        a0 += __int_as_float(e0.y) * bf2f(x[((size_t)e0.x << 6) + lane]);
        a1 += __int_as_float(e1.y) * bf2f(x[((size_t)e1.x << 6) + lane]);
        a2 += __int_as_float(e2.y) * bf2f(x[((size_t)e2.x << 6) + lane]);
        a3 += __int_as_float(e3.y) * bf2f(x[((size_t)e3.x << 6) + lane]);
        j += 4;
    }
    for (; j < end; ++j) {
        int2 e = cv[j];
        a0 += __int_as_float(e.y) * bf2f(x[((size_t)e.x << 6) + lane]);
    }
    return ((a0 + a1) + (a2 + a3)) + ((a4 + a5) + (a6 + a7));
}

// ---------------- layers 1..L-1: gather SpMV, write bf16 nxt only ----------------
__global__ __launch_bounds__(256)
void lgcn_spmv_mid(const int* __restrict__ rowptr,
                   const int2* __restrict__ cv,
                   const unsigned short* __restrict__ x,
                   unsigned short* __restrict__ nxt) {
    int t = blockIdx.x * blockDim.x + threadIdx.x;
    int wave = t >> 6;
    int lane = t & 63;
    if (wave >= N_NODES) return;
    int r = __builtin_amdgcn_readfirstlane(wave);
    float sum = spmv_row(cv, x, rowptr[r], rowptr[r + 1], lane);
    nxt[((size_t)r << 6) + lane] = f2bf(sum);
}

// ---------------- last layer: gather + fused final combine ----------------
// out = (e0_f32 + e1 + e2 + s3) * 0.25 ; x IS e2.
__global__ __launch_bounds__(256)
void lgcn_spmv_last(const int* __restrict__ rowptr,
                    const int2* __restrict__ cv,
                    const unsigned short* __restrict__ x,     // e2 (bf16)
                    const unsigned short* __restrict__ e1,    // layer-1 out (bf16)
                    const float* __restrict__ user_emb,
                    const float* __restrict__ item_emb,
                    float* __restrict__ out) {
    int t = blockIdx.x * blockDim.x + threadIdx.x;
    int wave = t >> 6;
    int lane = t & 63;
    if (wave >= N_NODES) return;
    int r = __builtin_amdgcn_readfirstlane(wave);
    float sum = spmv_row(cv, x, rowptr[r], rowptr[r + 1], lane);
    size_t o = ((size_t)r << 6) + lane;
    float e0 = (r < N_USERS) ? user_emb[o]
                             : item_emb[o - ((size_t)N_USERS << 6)];
    float v = ((e0 + bf2f(e1[o])) + bf2f(x[o])) + sum;
    out[o] = v * 0.25f;
}

// ---------------- fallback (atomic scatter, f32) ----------------
__global__ void lgcn_init(const float* __restrict__ user_emb,
                          const float* __restrict__ item_emb,
                          float* __restrict__ cur,
                          float* __restrict__ acc) {
    int i = blockIdx.x * blockDim.x + threadIdx.x;
    const int total = N_NODES * EMBED_DIM / 4;
    if (i >= total) return;
    const int user_elems = N_USERS * EMBED_DIM / 4;
    float4 v;
    if (i < user_elems) v = ((const float4*)user_emb)[i];
    else                v = ((const float4*)item_emb)[i - user_elems];
    ((float4*)cur)[i] = v;
    ((float4*)acc)[i] = v;
}

__global__ void lgcn_spmm_atomic(const int* __restrict__ row,
                                 const int* __restrict__ col,
                                 const float* __restrict__ val,
                                 const float* __restrict__ x,
                                 float* __restrict__ y) {
    long long t = (long long)blockIdx.x * blockDim.x + threadIdx.x;
    int e = (int)(t >> 6);
    int d = (int)(t & 63);
    if (e >= N_EDGES) return;
    atomicAdd(&y[(long long)row[e] * EMBED_DIM + d],
              val[e] * x[(long long)col[e] * EMBED_DIM + d]);
}

__global__ void lgcn_accum(const float* __restrict__ cur,
                           float* __restrict__ acc, float s) {
    int i = blockIdx.x * blockDim.x + threadIdx.x;
    const int total = N_NODES * EMBED_DIM / 4;
    if (i >= total) return;
    float4 a = ((const float4*)acc)[i];
    float4 c = ((const float4*)cur)[i];
    a.x = (a.x + c.x) * s; a.y = (a.y + c.y) * s;
    a.z = (a.z + c.z) * s; a.w = (a.w + c.w) * s;
    ((float4*)acc)[i] = a;
}

extern "C" void kernel_launch(void* const* d_in, const int* in_sizes, int n_in,
                              void* d_out, int out_size, void* d_ws, size_t ws_size,
                              hipStream_t stream) {
    const int*   adj_row  = (const int*)d_in[0];
    const int*   adj_col  = (const int*)d_in[1];
    const float* adj_val  = (const float*)d_in[2];
    const int*   adj_valI = (const int*)d_in[2];
    const float* user_emb = (const float*)d_in[3];
    const float* item_emb = (const float*)d_in[4];
    float* out = (float*)d_out;

    const size_t buf_elems = (size_t)N_NODES * EMBED_DIM;

    // ---- workspace layout ----
    char* wp = (char*)d_ws;
    int* bkt_cnt  = (int*)wp;  wp += (size_t)N_BKT * sizeof(int);
    int* bkt_base = (int*)wp;  wp += (size_t)(N_BKT + 1) * sizeof(int);
    int* bkt_cur  = (int*)wp;  wp += (size_t)N_BKT * sizeof(int);
    int* rowptr   = (int*)wp;  wp += (size_t)(N_NODES + 1) * sizeof(int);
    wp = (char*)(((size_t)wp + 63) & ~(size_t)63);
    int2* edges   = (int2*)wp; wp += (size_t)N_EDGES * sizeof(int2);
    wp = (char*)(((size_t)wp + 63) & ~(size_t)63);
    int2* csr_cv  = (int2*)wp; wp += (size_t)N_EDGES * sizeof(int2);
    wp = (char*)(((size_t)wp + 63) & ~(size_t)63);
    unsigned short* curb = (unsigned short*)wp; wp += buf_elems * sizeof(unsigned short);
    unsigned short* nxtb = (unsigned short*)wp; wp += buf_elems * sizeof(unsigned short);
    size_t needed = (size_t)(wp - (char*)d_ws);
    // e2 buffer aliases the (dead-after-sort) edges region
    unsigned short* e2b = (unsigned short*)edges;

    if (needed <= ws_size) {
        // ---- build: fused hist+init, scan, bucket partition, row sort ----
        hipMemsetAsync(bkt_cnt, 0, N_BKT * sizeof(int), stream);
        k_hist_init<<<NPB + INIT_BLOCKS, 256, 0, stream>>>(adj_row, bkt_cnt,
                                                           user_emb, item_emb, curb);
        k_scan<<<1, SCAN_T, 0, stream>>>(bkt_cnt, bkt_base, bkt_cur);
        k_part<<<NPB, 256, 0, stream>>>(adj_row, adj_col, adj_valI, bkt_cur, edges);
        k_sort<<<N_BKT, 256, 0, stream>>>(bkt_base, edges, csr_cv, rowptr);

        // ---- 3 gather-SpMV layers; acc deferred into the last ----
        const long long tthreads = (long long)N_NODES * 64;
        const int nblk = (int)((tthreads + 255) / 256);
        // L1: curb -> nxtb (e1)
        lgcn_spmv_mid<<<nblk, 256, 0, stream>>>(rowptr, csr_cv, curb, nxtb);
        // L2: nxtb -> e2b (aliases edges)
        lgcn_spmv_mid<<<nblk, 256, 0, stream>>>(rowptr, csr_cv, nxtb, e2b);
        // L3: gather from e2b, combine with e0 (f32 inputs) + e1 + e2 -> out
        lgcn_spmv_last<<<nblk, 256, 0, stream>>>(rowptr, csr_cv, e2b, nxtb,
                                                 user_emb, item_emb, out);
    } else {
        // ---- fallback: atomic path (f32) ----
        float* curF = (float*)d_ws;
        float* nxtF = curF + buf_elems;
        const int total = N_NODES * EMBED_DIM / 4;
        lgcn_init<<<(total + 255) / 256, 256, 0, stream>>>(user_emb, item_emb, curF, out);
        float* a = curF; float* b = nxtF;
        for (int layer = 0; layer < N_LAYERS; ++layer) {
            hipMemsetAsync(b, 0, buf_elems * sizeof(float), stream);
            long long tthr = (long long)N_EDGES * 64;
            lgcn_spmm_atomic<<<(unsigned)((tthr + 255) / 256), 256, 0, stream>>>(
                adj_row, adj_col, adj_val, a, b);
            float s = (layer == N_LAYERS - 1) ? (1.0f / (N_LAYERS + 1)) : 1.0f;
            lgcn_accum<<<(total + 255) / 256, 256, 0, stream>>>(b, out, s);
            float* t = a; a = b; b = t;
        }
    }
}

// Round 12
// 603.340 us; speedup vs baseline: 8.7168x; 1.0664x over previous
//
#include <hip/hip_runtime.h>

#define N_USERS 100000
#define N_ITEMS 50000
#define N_NODES 150000
#define EMBED_DIM 64
#define N_EDGES 4800000
#define N_LAYERS 3

// two-level row radix: coarse buckets of 512 rows
#define CB_SHIFT 9
#define CB_ROWS (1 << CB_SHIFT)                          // 512
#define NC ((N_NODES + CB_ROWS - 1) >> CB_SHIFT)         // 293

#define EPB_A 16384                                      // edges per block (hist)
#define NPB_A ((N_EDGES + EPB_A - 1) / EPB_A)            // 293
#define EPB_C 8192                                       // edges per block (partition)
#define NPB_C ((N_EDGES + EPB_C - 1) / EPB_C)            // 586
#define INIT_BLOCKS ((N_NODES * EMBED_DIM / 4 + 255) / 256)   // 9375

// ---------- bf16 helpers (RNE) ----------
__device__ __forceinline__ unsigned short f2bf(float f) {
    unsigned u = __float_as_uint(f);
    u += 0x7fffu + ((u >> 16) & 1u);
    return (unsigned short)(u >> 16);
}
__device__ __forceinline__ float bf2f(unsigned short h) {
    return __uint_as_float((unsigned)h << 16);
}

// ---------------- fused: coarse histogram + init cur0=bf16(emb) ----------------
__global__ __launch_bounds__(256)
void k_hist_init(const int* __restrict__ row, int* __restrict__ c_cnt,
                 const float* __restrict__ user_emb,
                 const float* __restrict__ item_emb,
                 unsigned short* __restrict__ curb) {
    __shared__ int h[NC];
    int blk = blockIdx.x;
    if (blk < NPB_A) {
        for (int i = threadIdx.x; i < NC; i += 256) h[i] = 0;
        __syncthreads();
        int e0 = blk * EPB_A;
        int e1 = e0 + EPB_A; if (e1 > N_EDGES) e1 = N_EDGES;
        for (int e = e0 + threadIdx.x; e < e1; e += 256)
            atomicAdd(&h[row[e] >> CB_SHIFT], 1);
        __syncthreads();
        for (int i = threadIdx.x; i < NC; i += 256)
            if (h[i]) atomicAdd(&c_cnt[i], h[i]);
    } else {
        int i = (blk - NPB_A) * 256 + threadIdx.x;
        const int total = N_NODES * EMBED_DIM / 4;
        if (i >= total) return;
        const int user_elems = N_USERS * EMBED_DIM / 4;
        float4 v;
        if (i < user_elems) v = ((const float4*)user_emb)[i];
        else                v = ((const float4*)item_emb)[i - user_elems];
        ushort4 o;
        o.x = f2bf(v.x); o.y = f2bf(v.y); o.z = f2bf(v.z); o.w = f2bf(v.w);
        ((ushort4*)curb)[i] = o;
    }
}

// ---------------- scan of 293 coarse counts ----------------
#define SCAN_T 256
#define SCAN_C ((NC + SCAN_T - 1) / SCAN_T)   // 2
__global__ void k_scan(const int* __restrict__ c_cnt,
                       int* __restrict__ cbase,
                       int* __restrict__ ccur) {
    __shared__ int part[SCAN_T];
    int t = threadIdx.x;
    int c0 = t * SCAN_C;
    int local[SCAN_C];
    int run = 0;
    for (int k = 0; k < SCAN_C; ++k) {
        int i = c0 + k;
        int v = (i < NC) ? c_cnt[i] : 0;
        local[k] = run;
        run += v;
    }
    part[t] = run;
    __syncthreads();
    if (t == 0) {
        int r2 = 0;
        for (int i = 0; i < SCAN_T; ++i) { int v = part[i]; part[i] = r2; r2 += v; }
    }
    __syncthreads();
    int base = part[t];
    for (int k = 0; k < SCAN_C; ++k) {
        int i = c0 + k;
        if (i < NC) {
            int v = base + local[k];
            cbase[i] = v;
            ccur[i]  = v;
        }
    }
    if (t == 0) cbase[NC] = N_EDGES;
}

// ---------------- coarse partition into 293 segments ----------------
// packed edge: (col << 9) | row_local(9b), val bits (int2)
__global__ __launch_bounds__(256)
void k_part_c(const int* __restrict__ row,
              const int* __restrict__ col,
              const int* __restrict__ valI,
              int* __restrict__ ccur,
              int2* __restrict__ edges) {
    __shared__ int h[NC];
    __shared__ int off[NC];
    int e0 = blockIdx.x * EPB_C;
    int e1 = e0 + EPB_C; if (e1 > N_EDGES) e1 = N_EDGES;
    for (int i = threadIdx.x; i < NC; i += 256) h[i] = 0;
    __syncthreads();
    for (int e = e0 + threadIdx.x; e < e1; e += 256)
        atomicAdd(&h[row[e] >> CB_SHIFT], 1);
    __syncthreads();
    for (int i = threadIdx.x; i < NC; i += 256)
        if (h[i]) off[i] = atomicAdd(&ccur[i], h[i]);
    __syncthreads();
    for (int e = e0 + threadIdx.x; e < e1; e += 256) {
        int r = row[e];
        int cb = r >> CB_SHIFT;
        int p = atomicAdd(&off[cb], 1);
        edges[p] = make_int2((col[e] << CB_SHIFT) | (r & (CB_ROWS - 1)), valI[e]);
    }
}

// ---------------- fine counting sort within each coarse segment ------------
// one 512-thread block per coarse bucket; segment ~131KB stays L2-local, so
// scatter writes fill lines before eviction (no write amplification).
__global__ __launch_bounds__(512)
void k_sort_c(const int* __restrict__ cbase,
              const int2* __restrict__ edges,
              int2* __restrict__ csr,
              int* __restrict__ rowptr) {
    __shared__ int h[CB_ROWS];
    __shared__ int off[CB_ROWS];
    int b = blockIdx.x;
    int seg0 = cbase[b], seg1 = cbase[b + 1];
    h[threadIdx.x] = 0;
    __syncthreads();
    for (int e = seg0 + threadIdx.x; e < seg1; e += 512)
        atomicAdd(&h[edges[e].x & (CB_ROWS - 1)], 1);
    __syncthreads();
    // Hillis-Steele inclusive scan over 512 bins
    for (int o = 1; o < CB_ROWS; o <<= 1) {
        int t = (threadIdx.x >= o) ? h[threadIdx.x - o] : 0;
        __syncthreads();
        h[threadIdx.x] += t;
        __syncthreads();
    }
    int row0 = b << CB_SHIFT;
    int nrows = N_NODES - row0; if (nrows > CB_ROWS) nrows = CB_ROWS;
    int excl = threadIdx.x ? h[threadIdx.x - 1] : 0;
    off[threadIdx.x] = excl;
    if (threadIdx.x < nrows) rowptr[row0 + threadIdx.x] = seg0 + excl;
    __syncthreads();
    for (int e = seg0 + threadIdx.x; e < seg1; e += 512) {
        int2 ee = edges[e];
        int rl = ee.x & (CB_ROWS - 1);
        int p = atomicAdd(&off[rl], 1);
        csr[seg0 + p] = make_int2(ee.x >> CB_SHIFT, ee.y);   // (col, val bits)
    }
    if (b == NC - 1 && threadIdx.x == 0) rowptr[N_NODES] = N_EDGES;
}

// ---------------- gather core: 8-deep MLP dot over one row ----------------
__device__ __forceinline__ float spmv_row(const int2* __restrict__ cv,
                                          const unsigned short* __restrict__ x,
                                          int start, int end, int lane) {
    float a0 = 0.f, a1 = 0.f, a2 = 0.f, a3 = 0.f;
    float a4 = 0.f, a5 = 0.f, a6 = 0.f, a7 = 0.f;
    int j = start;
    for (; j + 8 <= end; j += 8) {
        int2 e0 = cv[j + 0], e1 = cv[j + 1], e2 = cv[j + 2], e3 = cv[j + 3];
        int2 e4 = cv[j + 4], e5 = cv[j + 5], e6 = cv[j + 6], e7 = cv[j + 7];
        float x0 = bf2f(x[((size_t)e0.x << 6) + lane]);
        float x1 = bf2f(x[((size_t)e1.x << 6) + lane]);
        float x2 = bf2f(x[((size_t)e2.x << 6) + lane]);
        float x3 = bf2f(x[((size_t)e3.x << 6) + lane]);
        float x4 = bf2f(x[((size_t)e4.x << 6) + lane]);
        float x5 = bf2f(x[((size_t)e5.x << 6) + lane]);
        float x6 = bf2f(x[((size_t)e6.x << 6) + lane]);
        float x7 = bf2f(x[((size_t)e7.x << 6) + lane]);
        a0 += __int_as_float(e0.y) * x0;
        a1 += __int_as_float(e1.y) * x1;
        a2 += __int_as_float(e2.y) * x2;
        a3 += __int_as_float(e3.y) * x3;
        a4 += __int_as_float(e4.y) * x4;
        a5 += __int_as_float(e5.y) * x5;
        a6 += __int_as_float(e6.y) * x6;
        a7 += __int_as_float(e7.y) * x7;
    }
    if (j + 4 <= end) {
        int2 e0 = cv[j + 0], e1 = cv[j + 1], e2 = cv[j + 2], e3 = cv[j + 3];
        a0 += __int_as_float(e0.y) * bf2f(x[((size_t)e0.x << 6) + lane]);
        a1 += __int_as_float(e1.y) * bf2f(x[((size_t)e1.x << 6) + lane]);
        a2 += __int_as_float(e2.y) * bf2f(x[((size_t)e2.x << 6) + lane]);
        a3 += __int_as_float(e3.y) * bf2f(x[((size_t)e3.x << 6) + lane]);
        j += 4;
    }
    for (; j < end; ++j) {
        int2 e = cv[j];
        a0 += __int_as_float(e.y) * bf2f(x[((size_t)e.x << 6) + lane]);
    }
    return ((a0 + a1) + (a2 + a3)) + ((a4 + a5) + (a6 + a7));
}

// ---------------- layers 1..L-1: gather SpMV, write bf16 nxt only ----------------
__global__ __launch_bounds__(256)
void lgcn_spmv_mid(const int* __restrict__ rowptr,
                   const int2* __restrict__ cv,
                   const unsigned short* __restrict__ x,
                   unsigned short* __restrict__ nxt) {
    int t = blockIdx.x * blockDim.x + threadIdx.x;
    int wave = t >> 6;
    int lane = t & 63;
    if (wave >= N_NODES) return;
    int r = __builtin_amdgcn_readfirstlane(wave);
    float sum = spmv_row(cv, x, rowptr[r], rowptr[r + 1], lane);
    nxt[((size_t)r << 6) + lane] = f2bf(sum);
}

// ---------------- last layer: gather + fused final combine ----------------
// out = (e0_f32 + e1 + e2 + s3) * 0.25 ; x IS e2.
__global__ __launch_bounds__(256)
void lgcn_spmv_last(const int* __restrict__ rowptr,
                    const int2* __restrict__ cv,
                    const unsigned short* __restrict__ x,     // e2 (bf16)
                    const unsigned short* __restrict__ e1,    // layer-1 out (bf16)
                    const float* __restrict__ user_emb,
                    const float* __restrict__ item_emb,
                    float* __restrict__ out) {
    int t = blockIdx.x * blockDim.x + threadIdx.x;
    int wave = t >> 6;
    int lane = t & 63;
    if (wave >= N_NODES) return;
    int r = __builtin_amdgcn_readfirstlane(wave);
    float sum = spmv_row(cv, x, rowptr[r], rowptr[r + 1], lane);
    size_t o = ((size_t)r << 6) + lane;
    float e0 = (r < N_USERS) ? user_emb[o]
                             : item_emb[o - ((size_t)N_USERS << 6)];
    float v = ((e0 + bf2f(e1[o])) + bf2f(x[o])) + sum;
    out[o] = v * 0.25f;
}

// ---------------- fallback (atomic scatter, f32) ----------------
__global__ void lgcn_init(const float* __restrict__ user_emb,
                          const float* __restrict__ item_emb,
                          float* __restrict__ cur,
                          float* __restrict__ acc) {
    int i = blockIdx.x * blockDim.x + threadIdx.x;
    const int total = N_NODES * EMBED_DIM / 4;
    if (i >= total) return;
    const int user_elems = N_USERS * EMBED_DIM / 4;
    float4 v;
    if (i < user_elems) v = ((const float4*)user_emb)[i];
    else                v = ((const float4*)item_emb)[i - user_elems];
    ((float4*)cur)[i] = v;
    ((float4*)acc)[i] = v;
}

__global__ void lgcn_spmm_atomic(const int* __restrict__ row,
                                 const int* __restrict__ col,
                                 const float* __restrict__ val,
                                 const float* __restrict__ x,
                                 float* __restrict__ y) {
    long long t = (long long)blockIdx.x * blockDim.x + threadIdx.x;
    int e = (int)(t >> 6);
    int d = (int)(t & 63);
    if (e >= N_EDGES) return;
    atomicAdd(&y[(long long)row[e] * EMBED_DIM + d],
              val[e] * x[(long long)col[e] * EMBED_DIM + d]);
}

__global__ void lgcn_accum(const float* __restrict__ cur,
                           float* __restrict__ acc, float s) {
    int i = blockIdx.x * blockDim.x + threadIdx.x;
    const int total = N_NODES * EMBED_DIM / 4;
    if (i >= total) return;
    float4 a = ((const float4*)acc)[i];
    float4 c = ((const float4*)cur)[i];
    a.x = (a.x + c.x) * s; a.y = (a.y + c.y) * s;
    a.z = (a.z + c.z) * s; a.w = (a.w + c.w) * s;
    ((float4*)acc)[i] = a;
}

extern "C" void kernel_launch(void* const* d_in, const int* in_sizes, int n_in,
                              void* d_out, int out_size, void* d_ws, size_t ws_size,
                              hipStream_t stream) {
    const int*   adj_row  = (const int*)d_in[0];
    const int*   adj_col  = (const int*)d_in[1];
    const float* adj_val  = (const float*)d_in[2];
    const int*   adj_valI = (const int*)d_in[2];
    const float* user_emb = (const float*)d_in[3];
    const float* item_emb = (const float*)d_in[4];
    float* out = (float*)d_out;

    const size_t buf_elems = (size_t)N_NODES * EMBED_DIM;

    // ---- workspace layout ----
    char* wp = (char*)d_ws;
    int* c_cnt  = (int*)wp;  wp += (size_t)NC * sizeof(int);
    int* cbase  = (int*)wp;  wp += (size_t)(NC + 1) * sizeof(int);
    int* ccur   = (int*)wp;  wp += (size_t)NC * sizeof(int);
    int* rowptr = (int*)wp;  wp += (size_t)(N_NODES + 1) * sizeof(int);
    wp = (char*)(((size_t)wp + 63) & ~(size_t)63);
    int2* edges  = (int2*)wp; wp += (size_t)N_EDGES * sizeof(int2);
    wp = (char*)(((size_t)wp + 63) & ~(size_t)63);
    int2* csr_cv = (int2*)wp; wp += (size_t)N_EDGES * sizeof(int2);
    wp = (char*)(((size_t)wp + 63) & ~(size_t)63);
    unsigned short* curb = (unsigned short*)wp; wp += buf_elems * sizeof(unsigned short);
    unsigned short* nxtb = (unsigned short*)wp; wp += buf_elems * sizeof(unsigned short);
    size_t needed = (size_t)(wp - (char*)d_ws);
    // e2 buffer aliases the (dead-after-sort) edges region
    unsigned short* e2b = (unsigned short*)edges;

    if (needed <= ws_size) {
        // ---- build: fused hist+init, scan, coarse partition, fine sort ----
        hipMemsetAsync(c_cnt, 0, NC * sizeof(int), stream);
        k_hist_init<<<NPB_A + INIT_BLOCKS, 256, 0, stream>>>(adj_row, c_cnt,
                                                             user_emb, item_emb, curb);
        k_scan<<<1, SCAN_T, 0, stream>>>(c_cnt, cbase, ccur);
        k_part_c<<<NPB_C, 256, 0, stream>>>(adj_row, adj_col, adj_valI, ccur, edges);
        k_sort_c<<<NC, 512, 0, stream>>>(cbase, edges, csr_cv, rowptr);

        // ---- 3 gather-SpMV layers; acc deferred into the last ----
        const long long tthreads = (long long)N_NODES * 64;
        const int nblk = (int)((tthreads + 255) / 256);
        // L1: curb -> nxtb (e1)
        lgcn_spmv_mid<<<nblk, 256, 0, stream>>>(rowptr, csr_cv, curb, nxtb);
        // L2: nxtb -> e2b (aliases edges)
        lgcn_spmv_mid<<<nblk, 256, 0, stream>>>(rowptr, csr_cv, nxtb, e2b);
        // L3: gather from e2b, combine with e0 (f32 inputs) + e1 + e2 -> out
        lgcn_spmv_last<<<nblk, 256, 0, stream>>>(rowptr, csr_cv, e2b, nxtb,
                                                 user_emb, item_emb, out);
    } else {
        // ---- fallback: atomic path (f32) ----
        float* curF = (float*)d_ws;
        float* nxtF = curF + buf_elems;
        const int total = N_NODES * EMBED_DIM / 4;
        lgcn_init<<<(total + 255) / 256, 256, 0, stream>>>(user_emb, item_emb, curF, out);
        float* a = curF; float* b = nxtF;
        for (int layer = 0; layer < N_LAYERS; ++layer) {
            hipMemsetAsync(b, 0, buf_elems * sizeof(float), stream);
            long long tthr = (long long)N_EDGES * 64;
            lgcn_spmm_atomic<<<(unsigned)((tthr + 255) / 256), 256, 0, stream>>>(
                adj_row, adj_col, adj_val, a, b);
            float s = (layer == N_LAYERS - 1) ? (1.0f / (N_LAYERS + 1)) : 1.0f;
            lgcn_accum<<<(total + 255) / 256, 256, 0, stream>>>(b, out, s);
            float* t = a; a = b; b = t;
        }
    }
}